// Round 5
// baseline (264.921 us; speedup 1.0000x reference)
//
#include <hip/hip_runtime.h>
#include <hip/hip_bf16.h>

// AdditiveAttention: B=8, Q=128, V=512, H=512.
// out = [context (B*Q*H) | weights (B*Q*V)] fp32.
// ws: qp [1024*512] f32 @0, vp [4096*512] f32 @2MB (10MB).
// bc dropped (softmax shift-invariant); sum_h wc[h] const also cancels.
// Score math: tanh(y)=1-2r, r=1/(2^(C*y)+1), C=2*log2(e);
//   softmax arg = -C * sum_h wc[h]*r  (consts dropped).
// R5: plain launch_bounds on 512-thr kernels ((,N) hint = CUDA minBlocks
//   semantics; R2's (512,4) -> 64-reg cap -> spills at need~100).
// R7: attn split into score/finish kernels. R4 showed score is latency-
//   bound at 4 waves/SIMD (VALUBusy 45%), and the 512-block grid caps
//   waves/CU at 16 regardless of VGPR. attn_score: grid (512 qpairs x
//   4 slot-chunks) of 256 thr = 8 blocks/CU, NU=2 (~50 live regs),
//   (256,8) -> 64-reg cap (feasible -> no spill) -> 32 waves/CU.
//   Raw scores staged slot-ordered in out_w (2MB, exact fit), then
//   attn_finish does softmax + weight rows + context.

#define C_SCALE 2.8853900817779268f

typedef __attribute__((ext_vector_type(8))) short short8;
typedef __attribute__((ext_vector_type(4))) float f32x4;

__device__ __forceinline__ float fexp2(float x) { return __builtin_amdgcn_exp2f(x); }
__device__ __forceinline__ float frcp(float x)  { return __builtin_amdgcn_rcpf(x); }

// fp32->bf16 split: hi = RNE(x); lo = trunc_bf16(x - hi).
__device__ __forceinline__ void bf_split(float x, short& hi, short& lo) {
  unsigned u = __builtin_bit_cast(unsigned, x);
  unsigned r = u + 0x7fffu + ((u >> 16) & 1u);
  hi = (short)(r >> 16);
  float hf = __builtin_bit_cast(float, r & 0xffff0000u);
  lo = (short)(__builtin_bit_cast(unsigned, x - hf) >> 16);
}

// ---------------- split-bf16 MFMA GEMM ---------------------------------------
// out[m][n] = sum_k A[m][k]*W[n][k] + bias[n].  N=K=512.
// x = hi + lo (both bf16); D = Ahi*Whi + Ahi*Wlo + Alo*Whi (lo*lo dropped).
// 64x64 tile, KC=64. by<16 -> query rows (qp), else values rows (vp).
// LDS rows padded to 72 shorts (144B).
__global__ __launch_bounds__(256) void proj_gemm_mfma(
    const float* __restrict__ query, const float* __restrict__ values,
    const float* __restrict__ Wq, const float* __restrict__ Wv,
    const float* __restrict__ bq, const float* __restrict__ bv,
    float* __restrict__ qp, float* __restrict__ vp)
{
  __shared__ short sAhi[64 * 72];
  __shared__ short sAlo[64 * 72];
  __shared__ short sWhi[64 * 72];
  __shared__ short sWlo[64 * 72];

  const int t    = threadIdx.x;
  const int lane = t & 63;
  const int w    = t >> 6;                  // wave 0..3
  const int by   = blockIdx.y;
  const bool isQ = (by < 16);
  const float* A    = isQ ? query : values;
  const float* W    = isQ ? Wq : Wv;
  const float* bias = isQ ? bq : bv;
  float*       out  = isQ ? qp : vp;
  const int m0 = (isQ ? by : (by - 16)) << 6;
  const int n0 = blockIdx.x << 6;

  // staging map: thread t, iter p: row = t>>2 (64 rows), f4-col = p*4 + (t&3)
  const int srow = t >> 2, scol = t & 3;
  const float* Ap = A + (size_t)(m0 + srow) * 512 + (scol << 2);
  const float* Wp = W + (size_t)(n0 + srow) * 512 + (scol << 2);

  const int mw = (w & 1) << 5, nw = (w >> 1) << 5;   // wave's 32x32 quadrant
  const int frow = lane & 15, fquad = lane >> 4;

  f32x4 acc[2][2] = {};
  float4 pfA[4], pfW[4];
#pragma unroll
  for (int p = 0; p < 4; ++p) {
    pfA[p] = *(const float4*)(Ap + (p << 4));
    pfW[p] = *(const float4*)(Wp + (p << 4));
  }

  for (int kc = 0; kc < 512; kc += 64) {
    __syncthreads();
#pragma unroll
    for (int p = 0; p < 4; ++p) {
      float av[4] = {pfA[p].x, pfA[p].y, pfA[p].z, pfA[p].w};
      float wv[4] = {pfW[p].x, pfW[p].y, pfW[p].z, pfW[p].w};
      short4 ah, al, wh, wl;
      short* ahp = (short*)&ah; short* alp = (short*)&al;
      short* whp = (short*)&wh; short* wlp = (short*)&wl;
#pragma unroll
      for (int k = 0; k < 4; ++k) {
        bf_split(av[k], ahp[k], alp[k]);
        bf_split(wv[k], whp[k], wlp[k]);
      }
      const int ofs = srow * 72 + ((p << 2) + scol) * 4;
      *(short4*)&sAhi[ofs] = ah; *(short4*)&sAlo[ofs] = al;
      *(short4*)&sWhi[ofs] = wh; *(short4*)&sWlo[ofs] = wl;
    }
    __syncthreads();
    if (kc + 64 < 512) {
#pragma unroll
      for (int p = 0; p < 4; ++p) {
        pfA[p] = *(const float4*)(Ap + kc + 64 + (p << 4));
        pfW[p] = *(const float4*)(Wp + kc + 64 + (p << 4));
      }
    }
#pragma unroll
    for (int kb = 0; kb < 2; ++kb) {
      const int ko = kb * 32 + fquad * 8;
      short8 ahi[2], alo[2], whi[2], wlo[2];
#pragma unroll
      for (int mt = 0; mt < 2; ++mt) {
        const int r = (mw + mt * 16 + frow) * 72 + ko;
        ahi[mt] = *(const short8*)&sAhi[r];
        alo[mt] = *(const short8*)&sAlo[r];
      }
#pragma unroll
      for (int nt = 0; nt < 2; ++nt) {
        const int r = (nw + nt * 16 + frow) * 72 + ko;
        whi[nt] = *(const short8*)&sWhi[r];
        wlo[nt] = *(const short8*)&sWlo[r];
      }
#pragma unroll
      for (int mt = 0; mt < 2; ++mt)
#pragma unroll
        for (int nt = 0; nt < 2; ++nt) {
          acc[mt][nt] = __builtin_amdgcn_mfma_f32_16x16x32_bf16(
              alo[mt], whi[nt], acc[mt][nt], 0, 0, 0);
          acc[mt][nt] = __builtin_amdgcn_mfma_f32_16x16x32_bf16(
              ahi[mt], wlo[nt], acc[mt][nt], 0, 0, 0);
          acc[mt][nt] = __builtin_amdgcn_mfma_f32_16x16x32_bf16(
              ahi[mt], whi[nt], acc[mt][nt], 0, 0, 0);
        }
    }
  }

  // epilogue: C/D layout col = lane&15, row = (lane>>4)*4 + reg
#pragma unroll
  for (int nt = 0; nt < 2; ++nt) {
    const int n = n0 + nw + nt * 16 + frow;
    const float bn = bias[n];
#pragma unroll
    for (int mt = 0; mt < 2; ++mt) {
      float vreg[4] = {acc[mt][nt].x, acc[mt][nt].y, acc[mt][nt].z, acc[mt][nt].w};
#pragma unroll
      for (int r = 0; r < 4; ++r) {
        const int m = m0 + mw + mt * 16 + fquad * 4 + r;
        out[(size_t)m * 512 + n] = vreg[r] + bn;
      }
    }
  }
}

// ---------------- score chunk (NU slot-steps, 16 slots apart) ----------------
template<int NU>
__device__ __forceinline__ void score_chunkA(
    const float* __restrict__ vpb, const float* __restrict__ qr0,
    const float* __restrict__ wc, const int* idxs, float* __restrict__ ow0,
    int s00, int i0, int hi, int c4, int lane)
{
  int su[NU];
  unsigned voff[NU];
  float a0[NU], a1[NU];
#pragma unroll
  for (int u = 0; u < NU; ++u) {
    su[u] = s00 + ((i0 + u) << 4);
    voff[u] = ((unsigned)idxs[su[u] & 511] << 9) + (unsigned)c4;
    a0[u] = 0.f; a1[u] = 0.f;
  }
#pragma unroll
  for (int j = 0; j < 8; ++j) {
    const int hoff = (j << 6) + c4;
    float4 vv[NU];
#pragma unroll
    for (int u = 0; u < NU; ++u)
      vv[u] = *(const float4*)(vpb + voff[u] + (unsigned)(j << 6));
    const float4 q0v = *(const float4*)(qr0 + hoff);
    const float4 q1v = *(const float4*)(qr0 + 512 + hoff);
    const float4 wcv = *(const float4*)(wc + hoff);
    const float cq0[4] = {C_SCALE * q0v.x, C_SCALE * q0v.y,
                          C_SCALE * q0v.z, C_SCALE * q0v.w};
    const float dd[4]  = {fexp2(C_SCALE * (q1v.x - q0v.x)),
                          fexp2(C_SCALE * (q1v.y - q0v.y)),
                          fexp2(C_SCALE * (q1v.z - q0v.z)),
                          fexp2(C_SCALE * (q1v.w - q0v.w))};
    const float wc4[4] = {wcv.x, wcv.y, wcv.z, wcv.w};
#pragma unroll
    for (int u = 0; u < NU; ++u) {
      const float vq[4] = {vv[u].x, vv[u].y, vv[u].z, vv[u].w};
#pragma unroll
      for (int k = 0; k < 4; ++k) {
        float x0 = __builtin_fmaf(C_SCALE, vq[k], cq0[k]);
        float e0 = fexp2(x0);
        float e1 = e0 * dd[k];
        float d0 = e0 + 1.0f;
        float d1 = e1 + 1.0f;
        float P  = frcp(d0 * d1);          // pair-rcp: r0=d1*P, r1=d0*P
        a0[u] = __builtin_fmaf(wc4[k] * d1, P, a0[u]);
        a1[u] = __builtin_fmaf(wc4[k] * d0, P, a1[u]);
      }
    }
  }
#pragma unroll
  for (int u = 0; u < NU; ++u) {
    float s0 = a0[u], s1 = a1[u];
#pragma unroll
    for (int off = 1; off < 16; off <<= 1) {
      s0 += __shfl_xor(s0, off, 64);
      s1 += __shfl_xor(s1, off, 64);
    }
    if (su[u] < hi && (lane & 15) == (i0 + u)) {   // i0+u <= 7 < 16
      ow0[su[u]]       = s0;
      ow0[512 + su[u]] = s1;
    }
  }
}

// ---------------- attn kernel A: raw scores ----------------------------------
// Grid (512 qpairs, 4 slot-chunks) x 256 thr (4 waves) = 8 blocks/CU.
// (256,8): 32 waves/CU -> 64-reg cap; NU=2 keeps live state ~50 regs.
// Block covers slots [cnt*c/4, cnt*(c+1)/4); wave w, iter i owns slots
// lo + i*16 + w*4 + g (g = lane>>4); 16 h-lanes per slot (c4 = (lane&15)*4).
// Raw scores written slot-ordered into out_w rows (staging; finish rewrites).
__global__ __launch_bounds__(256, 8) void attn_score(
    const float* __restrict__ qp, const float* __restrict__ vp,
    const int* __restrict__ mask, const float* __restrict__ wc,
    float* __restrict__ out_w)
{
  __shared__ int idxs[512];
  __shared__ int cnt8[8];

  const int t    = threadIdx.x;
  const int lane = t & 63;
  const int w    = t >> 6;                 // 0..3
  const int b    = blockIdx.x & 7;
  const int qg   = blockIdx.x >> 3;
  const int rowbase = b * 128 + qg * 2;

  idxs[t] = 0; idxs[t + 256] = 0;
  const int mv0 = mask[b * 512 + t];
  const int mv1 = mask[b * 512 + 256 + t];
  const unsigned long long bal0 = __ballot(mv0 != 0);
  const unsigned long long bal1 = __ballot(mv1 != 0);
  if (lane == 0) { cnt8[w] = __popcll(bal0); cnt8[w + 4] = __popcll(bal1); }
  __syncthreads();
  int cnt = 0, off0 = 0, off4 = 0;
#pragma unroll
  for (int j = 0; j < 8; ++j) {
    if (j == w)     off0 = cnt;
    if (j == w + 4) off4 = cnt;
    cnt += cnt8[j];
  }
  if (mv0) idxs[off0 + __popcll(bal0 & ((1ull << lane) - 1ull))] = t;
  if (mv1) idxs[off4 + __popcll(bal1 & ((1ull << lane) - 1ull))] = t + 256;
  __syncthreads();

  const int c  = blockIdx.y;               // slot-chunk 0..3
  const int lo = (cnt * c) >> 2;
  const int hi = (cnt * (c + 1)) >> 2;
  const int NI = (hi - lo + 15) >> 4;      // 16-slot steps (<=8)
  const int g  = lane >> 4;
  const int c4 = (lane & 15) << 2;
  const int s00 = lo + (w << 2) + g;

  const float* vpb = vp + (size_t)b * 512 * 512;
  const float* qr0 = qp + (size_t)rowbase * 512;
  float* ow0 = out_w + (size_t)rowbase * 512;

  int i0 = 0;
  for (; i0 + 2 <= NI; i0 += 2)
    score_chunkA<2>(vpb, qr0, wc, idxs, ow0, s00, i0, hi, c4, lane);
  for (; i0 < NI; ++i0)
    score_chunkA<1>(vpb, qr0, wc, idxs, ow0, s00, i0, hi, c4, lane);
}

// ---------------- attn kernel B: softmax + weights + context -----------------
// 512 blocks x 512 thr (8 waves). Reads slot-ordered raw scores from out_w,
// softmax (min-shift, invalid slots masked to +BIG), rewrites out_w rows
// coalesced via inverse map, context with wave-per-h-window.
__global__ __launch_bounds__(512) void attn_finish(
    const float* __restrict__ values, const int* __restrict__ mask,
    float* __restrict__ out_ctx, float* __restrict__ out_w)
{
  __shared__ int   idxs[512];
  __shared__ float wls2[512][2];    // final weights per slot, (q0,q1) pairs
  __shared__ int   cnt8[8];

  const int t    = threadIdx.x;
  const int lane = t & 63;
  const int w    = t >> 6;                 // 0..7
  const int b    = blockIdx.x & 7;
  const int qg   = blockIdx.x >> 3;
  const int rowbase = b * 128 + qg * 2;

  ((float*)wls2)[t]       = 0.f;
  ((float*)wls2)[t + 512] = 0.f;
  idxs[t] = 0;
  const int mv = mask[b * 512 + t];
  const unsigned long long bal = __ballot(mv != 0);
  if (lane == 0) cnt8[w] = __popcll(bal);
  __syncthreads();
  int cnt = 0, offw = 0;
#pragma unroll
  for (int j = 0; j < 8; ++j) { if (j == w) offw = cnt; cnt += cnt8[j]; }
  int iinv = -1;
  if (mv) {
    iinv = offw + __popcll(bal & ((1ull << lane) - 1ull));
    idxs[iinv] = t;
  }
  __syncthreads();

  // ---- softmax: waves 0-3 -> q0, 4-7 -> q1 (dup compute; waves 0/4 write)
  {
    const int mq = (w >= 4) ? 1 : 0;
    const float* srow = out_w + (size_t)(rowbase + mq) * 512;
    float4 u0 = ((const float4*)srow)[lane * 2];
    float4 u1 = ((const float4*)srow)[lane * 2 + 1];
    float s8[8] = {u0.x, u0.y, u0.z, u0.w, u1.x, u1.y, u1.z, u1.w};
#pragma unroll
    for (int k = 0; k < 8; ++k)
      if (lane * 8 + k >= cnt) s8[k] = 3.4e38f;           // mask garbage slots
    float m = s8[0];
#pragma unroll
    for (int k = 1; k < 8; ++k) m = fminf(m, s8[k]);      // min: weight=exp2(C*(m-s))
#pragma unroll
    for (int off = 1; off < 64; off <<= 1) m = fminf(m, __shfl_xor(m, off, 64));
    float e[8], S = 0.f;
#pragma unroll
    for (int k = 0; k < 8; ++k) { e[k] = fexp2(C_SCALE * (m - s8[k])); S += e[k]; }
#pragma unroll
    for (int off = 1; off < 64; off <<= 1) S += __shfl_xor(S, off, 64);
    const float rinv = frcp(S);
    if (w == 0 || w == 4) {
#pragma unroll
      for (int k = 0; k < 8; ++k) {
        const int s = lane * 8 + k;
        if (s < cnt) wls2[s][mq] = e[k] * rinv;
      }
    }
  }
  __syncthreads();

  // ---- final weight rows (coalesced; zeros where masked out)
  {
    float w0 = 0.f, w1 = 0.f;
    if (iinv >= 0) { w0 = wls2[iinv][0]; w1 = wls2[iinv][1]; }
    out_w[(size_t)rowbase * 512 + t]       = w0;
    out_w[(size_t)(rowbase + 1) * 512 + t] = w1;
  }

  // ---- context: wave w owns h-window [w*64, w*64+64)
  const int NC = (cnt + 3) >> 2;
  const int g  = lane >> 4;
  const int c4 = (lane & 15) << 2;
  const unsigned hbase = (unsigned)(w * 64 + c4);
  const float* vb = values + (size_t)b * 512 * 512;
  float c0[4] = {0.f, 0.f, 0.f, 0.f}, c1[4] = {0.f, 0.f, 0.f, 0.f};
#pragma unroll 4
  for (int i = 0; i < NC; ++i) {
    const int s = (i << 2) + g;
    const unsigned ro = ((unsigned)idxs[s] << 9) + hbase;
    const float2 wg = *(const float2*)&wls2[s][0];        // padded slots: 0
    const float4 v4 = *(const float4*)(vb + ro);
    float vv[4] = {v4.x, v4.y, v4.z, v4.w};
#pragma unroll
    for (int k = 0; k < 4; ++k) {
      c0[k] = __builtin_fmaf(wg.x, vv[k], c0[k]);
      c1[k] = __builtin_fmaf(wg.y, vv[k], c1[k]);
    }
  }
#pragma unroll
  for (int k = 0; k < 4; ++k) {                           // reduce over g
    c0[k] += __shfl_xor(c0[k], 16, 64); c0[k] += __shfl_xor(c0[k], 32, 64);
    c1[k] += __shfl_xor(c1[k], 16, 64); c1[k] += __shfl_xor(c1[k], 32, 64);
  }
  if (lane < 16) {
    float4 o0 = {c0[0], c0[1], c0[2], c0[3]};
    float4 o1 = {c1[0], c1[1], c1[2], c1[3]};
    *(float4*)(out_ctx + (size_t)rowbase * 512 + w * 64 + lane * 4)       = o0;
    *(float4*)(out_ctx + (size_t)(rowbase + 1) * 512 + w * 64 + lane * 4) = o1;
  }
}

extern "C" void kernel_launch(void* const* d_in, const int* in_sizes, int n_in,
                              void* d_out, int out_size, void* d_ws, size_t ws_size,
                              hipStream_t stream) {
  const float* query  = (const float*)d_in[0];
  const float* values = (const float*)d_in[1];
  const int*   mask   = (const int*)d_in[2];
  const float* Wq     = (const float*)d_in[3];
  const float* bq     = (const float*)d_in[4];
  const float* Wv     = (const float*)d_in[5];
  const float* bv     = (const float*)d_in[6];
  const float* wc     = (const float*)d_in[7];
  // d_in[8] = bc: no effect on outputs (softmax shift-invariance) -> dropped.

  float* out   = (float*)d_out;
  float* out_w = out + (size_t)8 * 128 * 512;
  float* qp    = (float*)d_ws;                 // 1024 x 512
  float* vp    = qp + (size_t)1024 * 512;      // 4096 x 512

  proj_gemm_mfma<<<dim3(8, 80), 256, 0, stream>>>(query, values, Wq, Wv, bq, bv, qp, vp);
  attn_score<<<dim3(512, 4), 256, 0, stream>>>(qp, vp, mask, wc, out_w);
  attn_finish<<<512, 512, 0, stream>>>(values, mask, out, out_w);
}

// Round 6
// 145.809 us; speedup vs baseline: 1.8169x; 1.8169x over previous
//
#include <hip/hip_runtime.h>
#include <hip/hip_bf16.h>

// AdditiveAttention: B=8, Q=128, V=512, H=512.
// out = [context (B*Q*H) | weights (B*Q*V)] fp32.
// ws: qp [1024*512] f32 @0, vp [4096*512] f32 @2MB (10MB).
// bc dropped (softmax shift-invariant); sum_h wc[h] const also cancels.
// Score math: tanh(y)=1-2r, r=1/(2^(C*y)+1), C=2*log2(e);
//   softmax arg = -C * sum_h wc[h]*r  (consts dropped).
// HARD RULE (R0..R5 evidence): NO min-occupancy arg in launch_bounds, ever.
//   Plain bounds (R0/R3/R4) = zero scratch; hinted (R1/R2/R5) = 9.6/118/576MB
//   spill traffic (R5: VGPR crushed to 32, WRITE 210MB, 163us).
// R8: R7's score/finish split retried with plain launch_bounds(256) on
//   attn_score -- the single variable that killed R5. Grid (512 qpairs x
//   4 slot-chunks) x 4 waves = up to 8 blocks/CU vs fused kernel's hard
//   2-block grid cap; score phase was latency-bound at 16 waves/CU (R4).

#define C_SCALE 2.8853900817779268f

typedef __attribute__((ext_vector_type(8))) short short8;
typedef __attribute__((ext_vector_type(4))) float f32x4;

__device__ __forceinline__ float fexp2(float x) { return __builtin_amdgcn_exp2f(x); }
__device__ __forceinline__ float frcp(float x)  { return __builtin_amdgcn_rcpf(x); }

// fp32->bf16 split: hi = RNE(x); lo = trunc_bf16(x - hi).
__device__ __forceinline__ void bf_split(float x, short& hi, short& lo) {
  unsigned u = __builtin_bit_cast(unsigned, x);
  unsigned r = u + 0x7fffu + ((u >> 16) & 1u);
  hi = (short)(r >> 16);
  float hf = __builtin_bit_cast(float, r & 0xffff0000u);
  lo = (short)(__builtin_bit_cast(unsigned, x - hf) >> 16);
}

// ---------------- split-bf16 MFMA GEMM ---------------------------------------
// out[m][n] = sum_k A[m][k]*W[n][k] + bias[n].  N=K=512.
// x = hi + lo (both bf16); D = Ahi*Whi + Ahi*Wlo + Alo*Whi (lo*lo dropped).
// 64x64 tile, KC=64. by<16 -> query rows (qp), else values rows (vp).
// LDS rows padded to 72 shorts (144B).
__global__ __launch_bounds__(256) void proj_gemm_mfma(
    const float* __restrict__ query, const float* __restrict__ values,
    const float* __restrict__ Wq, const float* __restrict__ Wv,
    const float* __restrict__ bq, const float* __restrict__ bv,
    float* __restrict__ qp, float* __restrict__ vp)
{
  __shared__ short sAhi[64 * 72];
  __shared__ short sAlo[64 * 72];
  __shared__ short sWhi[64 * 72];
  __shared__ short sWlo[64 * 72];

  const int t    = threadIdx.x;
  const int lane = t & 63;
  const int w    = t >> 6;                  // wave 0..3
  const int by   = blockIdx.y;
  const bool isQ = (by < 16);
  const float* A    = isQ ? query : values;
  const float* W    = isQ ? Wq : Wv;
  const float* bias = isQ ? bq : bv;
  float*       out  = isQ ? qp : vp;
  const int m0 = (isQ ? by : (by - 16)) << 6;
  const int n0 = blockIdx.x << 6;

  // staging map: thread t, iter p: row = t>>2 (64 rows), f4-col = p*4 + (t&3)
  const int srow = t >> 2, scol = t & 3;
  const float* Ap = A + (size_t)(m0 + srow) * 512 + (scol << 2);
  const float* Wp = W + (size_t)(n0 + srow) * 512 + (scol << 2);

  const int mw = (w & 1) << 5, nw = (w >> 1) << 5;   // wave's 32x32 quadrant
  const int frow = lane & 15, fquad = lane >> 4;

  f32x4 acc[2][2] = {};
  float4 pfA[4], pfW[4];
#pragma unroll
  for (int p = 0; p < 4; ++p) {
    pfA[p] = *(const float4*)(Ap + (p << 4));
    pfW[p] = *(const float4*)(Wp + (p << 4));
  }

  for (int kc = 0; kc < 512; kc += 64) {
    __syncthreads();
#pragma unroll
    for (int p = 0; p < 4; ++p) {
      float av[4] = {pfA[p].x, pfA[p].y, pfA[p].z, pfA[p].w};
      float wv[4] = {pfW[p].x, pfW[p].y, pfW[p].z, pfW[p].w};
      short4 ah, al, wh, wl;
      short* ahp = (short*)&ah; short* alp = (short*)&al;
      short* whp = (short*)&wh; short* wlp = (short*)&wl;
#pragma unroll
      for (int k = 0; k < 4; ++k) {
        bf_split(av[k], ahp[k], alp[k]);
        bf_split(wv[k], whp[k], wlp[k]);
      }
      const int ofs = srow * 72 + ((p << 2) + scol) * 4;
      *(short4*)&sAhi[ofs] = ah; *(short4*)&sAlo[ofs] = al;
      *(short4*)&sWhi[ofs] = wh; *(short4*)&sWlo[ofs] = wl;
    }
    __syncthreads();
    if (kc + 64 < 512) {
#pragma unroll
      for (int p = 0; p < 4; ++p) {
        pfA[p] = *(const float4*)(Ap + kc + 64 + (p << 4));
        pfW[p] = *(const float4*)(Wp + kc + 64 + (p << 4));
      }
    }
#pragma unroll
    for (int kb = 0; kb < 2; ++kb) {
      const int ko = kb * 32 + fquad * 8;
      short8 ahi[2], alo[2], whi[2], wlo[2];
#pragma unroll
      for (int mt = 0; mt < 2; ++mt) {
        const int r = (mw + mt * 16 + frow) * 72 + ko;
        ahi[mt] = *(const short8*)&sAhi[r];
        alo[mt] = *(const short8*)&sAlo[r];
      }
#pragma unroll
      for (int nt = 0; nt < 2; ++nt) {
        const int r = (nw + nt * 16 + frow) * 72 + ko;
        whi[nt] = *(const short8*)&sWhi[r];
        wlo[nt] = *(const short8*)&sWlo[r];
      }
#pragma unroll
      for (int mt = 0; mt < 2; ++mt)
#pragma unroll
        for (int nt = 0; nt < 2; ++nt) {
          acc[mt][nt] = __builtin_amdgcn_mfma_f32_16x16x32_bf16(
              alo[mt], whi[nt], acc[mt][nt], 0, 0, 0);
          acc[mt][nt] = __builtin_amdgcn_mfma_f32_16x16x32_bf16(
              ahi[mt], wlo[nt], acc[mt][nt], 0, 0, 0);
          acc[mt][nt] = __builtin_amdgcn_mfma_f32_16x16x32_bf16(
              ahi[mt], whi[nt], acc[mt][nt], 0, 0, 0);
        }
    }
  }

  // epilogue: C/D layout col = lane&15, row = (lane>>4)*4 + reg
#pragma unroll
  for (int nt = 0; nt < 2; ++nt) {
    const int n = n0 + nw + nt * 16 + frow;
    const float bn = bias[n];
#pragma unroll
    for (int mt = 0; mt < 2; ++mt) {
      float vreg[4] = {acc[mt][nt].x, acc[mt][nt].y, acc[mt][nt].z, acc[mt][nt].w};
#pragma unroll
      for (int r = 0; r < 4; ++r) {
        const int m = m0 + mw + mt * 16 + fquad * 4 + r;
        out[(size_t)m * 512 + n] = vreg[r] + bn;
      }
    }
  }
}

// ---------------- score chunk (NU slot-steps, 16 slots apart) ----------------
template<int NU>
__device__ __forceinline__ void score_chunkA(
    const float* __restrict__ vpb, const float* __restrict__ qr0,
    const float* __restrict__ wc, const int* idxs, float* __restrict__ ow0,
    int s00, int i0, int hi, int c4, int lane)
{
  int su[NU];
  unsigned voff[NU];
  float a0[NU], a1[NU];
#pragma unroll
  for (int u = 0; u < NU; ++u) {
    su[u] = s00 + ((i0 + u) << 4);
    voff[u] = ((unsigned)idxs[su[u] & 511] << 9) + (unsigned)c4;
    a0[u] = 0.f; a1[u] = 0.f;
  }
#pragma unroll
  for (int j = 0; j < 8; ++j) {
    const int hoff = (j << 6) + c4;
    float4 vv[NU];
#pragma unroll
    for (int u = 0; u < NU; ++u)
      vv[u] = *(const float4*)(vpb + voff[u] + (unsigned)(j << 6));
    const float4 q0v = *(const float4*)(qr0 + hoff);
    const float4 q1v = *(const float4*)(qr0 + 512 + hoff);
    const float4 wcv = *(const float4*)(wc + hoff);
    const float cq0[4] = {C_SCALE * q0v.x, C_SCALE * q0v.y,
                          C_SCALE * q0v.z, C_SCALE * q0v.w};
    const float dd[4]  = {fexp2(C_SCALE * (q1v.x - q0v.x)),
                          fexp2(C_SCALE * (q1v.y - q0v.y)),
                          fexp2(C_SCALE * (q1v.z - q0v.z)),
                          fexp2(C_SCALE * (q1v.w - q0v.w))};
    const float wc4[4] = {wcv.x, wcv.y, wcv.z, wcv.w};
#pragma unroll
    for (int u = 0; u < NU; ++u) {
      const float vq[4] = {vv[u].x, vv[u].y, vv[u].z, vv[u].w};
#pragma unroll
      for (int k = 0; k < 4; ++k) {
        float x0 = __builtin_fmaf(C_SCALE, vq[k], cq0[k]);
        float e0 = fexp2(x0);
        float e1 = e0 * dd[k];
        float d0 = e0 + 1.0f;
        float d1 = e1 + 1.0f;
        float P  = frcp(d0 * d1);          // pair-rcp: r0=d1*P, r1=d0*P
        a0[u] = __builtin_fmaf(wc4[k] * d1, P, a0[u]);
        a1[u] = __builtin_fmaf(wc4[k] * d0, P, a1[u]);
      }
    }
  }
#pragma unroll
  for (int u = 0; u < NU; ++u) {
    float s0 = a0[u], s1 = a1[u];
#pragma unroll
    for (int off = 1; off < 16; off <<= 1) {
      s0 += __shfl_xor(s0, off, 64);
      s1 += __shfl_xor(s1, off, 64);
    }
    if (su[u] < hi && (lane & 15) == (i0 + u)) {   // i0+u <= 7 < 16
      ow0[su[u]]       = s0;
      ow0[512 + su[u]] = s1;
    }
  }
}

// ---------------- attn kernel A: raw scores ----------------------------------
// Grid (512 qpairs, 4 slot-chunks) x 256 thr (4 waves) = up to 8 blocks/CU.
// PLAIN launch_bounds (no min-occupancy arg -- see HARD RULE above).
// Block covers slots [cnt*c/4, cnt*(c+1)/4); wave w, iter i owns slots
// lo + i*16 + w*4 + g (g = lane>>4); 16 h-lanes per slot (c4 = (lane&15)*4).
// Raw scores written slot-ordered into out_w rows (staging; finish rewrites).
__global__ __launch_bounds__(256) void attn_score(
    const float* __restrict__ qp, const float* __restrict__ vp,
    const int* __restrict__ mask, const float* __restrict__ wc,
    float* __restrict__ out_w)
{
  __shared__ int idxs[512];
  __shared__ int cnt8[8];

  const int t    = threadIdx.x;
  const int lane = t & 63;
  const int w    = t >> 6;                 // 0..3
  const int b    = blockIdx.x & 7;
  const int qg   = blockIdx.x >> 3;
  const int rowbase = b * 128 + qg * 2;

  idxs[t] = 0; idxs[t + 256] = 0;
  const int mv0 = mask[b * 512 + t];
  const int mv1 = mask[b * 512 + 256 + t];
  const unsigned long long bal0 = __ballot(mv0 != 0);
  const unsigned long long bal1 = __ballot(mv1 != 0);
  if (lane == 0) { cnt8[w] = __popcll(bal0); cnt8[w + 4] = __popcll(bal1); }
  __syncthreads();
  int cnt = 0, off0 = 0, off4 = 0;
#pragma unroll
  for (int j = 0; j < 8; ++j) {
    if (j == w)     off0 = cnt;
    if (j == w + 4) off4 = cnt;
    cnt += cnt8[j];
  }
  if (mv0) idxs[off0 + __popcll(bal0 & ((1ull << lane) - 1ull))] = t;
  if (mv1) idxs[off4 + __popcll(bal1 & ((1ull << lane) - 1ull))] = t + 256;
  __syncthreads();

  const int c  = blockIdx.y;               // slot-chunk 0..3
  const int lo = (cnt * c) >> 2;
  const int hi = (cnt * (c + 1)) >> 2;
  const int NI = (hi - lo + 15) >> 4;      // 16-slot steps (<=8)
  const int g  = lane >> 4;
  const int c4 = (lane & 15) << 2;
  const int s00 = lo + (w << 2) + g;

  const float* vpb = vp + (size_t)b * 512 * 512;
  const float* qr0 = qp + (size_t)rowbase * 512;
  float* ow0 = out_w + (size_t)rowbase * 512;

  int i0 = 0;
  for (; i0 + 2 <= NI; i0 += 2)
    score_chunkA<2>(vpb, qr0, wc, idxs, ow0, s00, i0, hi, c4, lane);
  for (; i0 < NI; ++i0)
    score_chunkA<1>(vpb, qr0, wc, idxs, ow0, s00, i0, hi, c4, lane);
}

// ---------------- attn kernel B: softmax + weights + context -----------------
// 512 blocks x 512 thr (8 waves). Reads slot-ordered raw scores from out_w,
// softmax (min-shift, invalid slots masked to +BIG), rewrites out_w rows
// coalesced via inverse map, context with wave-per-h-window.
__global__ __launch_bounds__(512) void attn_finish(
    const float* __restrict__ values, const int* __restrict__ mask,
    float* __restrict__ out_ctx, float* __restrict__ out_w)
{
  __shared__ int   idxs[512];
  __shared__ float wls2[512][2];    // final weights per slot, (q0,q1) pairs
  __shared__ int   cnt8[8];

  const int t    = threadIdx.x;
  const int lane = t & 63;
  const int w    = t >> 6;                 // 0..7
  const int b    = blockIdx.x & 7;
  const int qg   = blockIdx.x >> 3;
  const int rowbase = b * 128 + qg * 2;

  ((float*)wls2)[t]       = 0.f;
  ((float*)wls2)[t + 512] = 0.f;
  idxs[t] = 0;
  const int mv = mask[b * 512 + t];
  const unsigned long long bal = __ballot(mv != 0);
  if (lane == 0) cnt8[w] = __popcll(bal);
  __syncthreads();
  int cnt = 0, offw = 0;
#pragma unroll
  for (int j = 0; j < 8; ++j) { if (j == w) offw = cnt; cnt += cnt8[j]; }
  int iinv = -1;
  if (mv) {
    iinv = offw + __popcll(bal & ((1ull << lane) - 1ull));
    idxs[iinv] = t;
  }
  __syncthreads();

  // ---- softmax: waves 0-3 -> q0, 4-7 -> q1 (dup compute; waves 0/4 write)
  {
    const int mq = (w >= 4) ? 1 : 0;
    const float* srow = out_w + (size_t)(rowbase + mq) * 512;
    float4 u0 = ((const float4*)srow)[lane * 2];
    float4 u1 = ((const float4*)srow)[lane * 2 + 1];
    float s8[8] = {u0.x, u0.y, u0.z, u0.w, u1.x, u1.y, u1.z, u1.w};
#pragma unroll
    for (int k = 0; k < 8; ++k)
      if (lane * 8 + k >= cnt) s8[k] = 3.4e38f;           // mask garbage slots
    float m = s8[0];
#pragma unroll
    for (int k = 1; k < 8; ++k) m = fminf(m, s8[k]);      // min: weight=exp2(C*(m-s))
#pragma unroll
    for (int off = 1; off < 64; off <<= 1) m = fminf(m, __shfl_xor(m, off, 64));
    float e[8], S = 0.f;
#pragma unroll
    for (int k = 0; k < 8; ++k) { e[k] = fexp2(C_SCALE * (m - s8[k])); S += e[k]; }
#pragma unroll
    for (int off = 1; off < 64; off <<= 1) S += __shfl_xor(S, off, 64);
    const float rinv = frcp(S);
    if (w == 0 || w == 4) {
#pragma unroll
      for (int k = 0; k < 8; ++k) {
        const int s = lane * 8 + k;
        if (s < cnt) wls2[s][mq] = e[k] * rinv;
      }
    }
  }
  __syncthreads();

  // ---- final weight rows (coalesced; zeros where masked out)
  {
    float w0 = 0.f, w1 = 0.f;
    if (iinv >= 0) { w0 = wls2[iinv][0]; w1 = wls2[iinv][1]; }
    out_w[(size_t)rowbase * 512 + t]       = w0;
    out_w[(size_t)(rowbase + 1) * 512 + t] = w1;
  }

  // ---- context: wave w owns h-window [w*64, w*64+64)
  const int NC = (cnt + 3) >> 2;
  const int g  = lane >> 4;
  const int c4 = (lane & 15) << 2;
  const unsigned hbase = (unsigned)(w * 64 + c4);
  const float* vb = values + (size_t)b * 512 * 512;
  float c0[4] = {0.f, 0.f, 0.f, 0.f}, c1[4] = {0.f, 0.f, 0.f, 0.f};
#pragma unroll 4
  for (int i = 0; i < NC; ++i) {
    const int s = (i << 2) + g;
    const unsigned ro = ((unsigned)idxs[s] << 9) + hbase;
    const float2 wg = *(const float2*)&wls2[s][0];        // padded slots: 0
    const float4 v4 = *(const float4*)(vb + ro);
    float vv[4] = {v4.x, v4.y, v4.z, v4.w};
#pragma unroll
    for (int k = 0; k < 4; ++k) {
      c0[k] = __builtin_fmaf(wg.x, vv[k], c0[k]);
      c1[k] = __builtin_fmaf(wg.y, vv[k], c1[k]);
    }
  }
#pragma unroll
  for (int k = 0; k < 4; ++k) {                           // reduce over g
    c0[k] += __shfl_xor(c0[k], 16, 64); c0[k] += __shfl_xor(c0[k], 32, 64);
    c1[k] += __shfl_xor(c1[k], 16, 64); c1[k] += __shfl_xor(c1[k], 32, 64);
  }
  if (lane < 16) {
    float4 o0 = {c0[0], c0[1], c0[2], c0[3]};
    float4 o1 = {c1[0], c1[1], c1[2], c1[3]};
    *(float4*)(out_ctx + (size_t)rowbase * 512 + w * 64 + lane * 4)       = o0;
    *(float4*)(out_ctx + (size_t)(rowbase + 1) * 512 + w * 64 + lane * 4) = o1;
  }
}

extern "C" void kernel_launch(void* const* d_in, const int* in_sizes, int n_in,
                              void* d_out, int out_size, void* d_ws, size_t ws_size,
                              hipStream_t stream) {
  const float* query  = (const float*)d_in[0];
  const float* values = (const float*)d_in[1];
  const int*   mask   = (const int*)d_in[2];
  const float* Wq     = (const float*)d_in[3];
  const float* bq     = (const float*)d_in[4];
  const float* Wv     = (const float*)d_in[5];
  const float* bv     = (const float*)d_in[6];
  const float* wc     = (const float*)d_in[7];
  // d_in[8] = bc: no effect on outputs (softmax shift-invariance) -> dropped.

  float* out   = (float*)d_out;
  float* out_w = out + (size_t)8 * 128 * 512;
  float* qp    = (float*)d_ws;                 // 1024 x 512
  float* vp    = qp + (size_t)1024 * 512;      // 4096 x 512

  proj_gemm_mfma<<<dim3(8, 80), 256, 0, stream>>>(query, values, Wq, Wv, bq, bv, qp, vp);
  attn_score<<<dim3(512, 4), 256, 0, stream>>>(qp, vp, mask, wc, out_w);
  attn_finish<<<512, 512, 0, stream>>>(values, mask, out, out_w);
}